// Round 19
// baseline (1892.772 us; speedup 1.0000x reference)
//
#include <hip/hip_runtime.h>
#include <hip/hip_bf16.h>

typedef __bf16 bf16_t;
typedef bf16_t bf16x8 __attribute__((ext_vector_type(8)));
typedef float f32x4 __attribute__((ext_vector_type(4)));
typedef unsigned int u32x4 __attribute__((ext_vector_type(4)));

// ---------------------------------------------------------------------------
__device__ __forceinline__ void load_lds16(const bf16_t* g, bf16_t* l) {
  __builtin_amdgcn_global_load_lds(
      (const __attribute__((address_space(1))) unsigned int*)g,
      (__attribute__((address_space(3))) unsigned int*)l,
      16, 0, 0);
}

// ---------------------------------------------------------------------------
__global__ void conv_f32_bf16(const float* __restrict__ src,
                              bf16_t* __restrict__ dst, long n) {
  long i = ((long)blockIdx.x * blockDim.x + threadIdx.x) * 8;
  if (i + 7 >= n) return;
  float4 a = *(const float4*)(src + i);
  float4 b = *(const float4*)(src + i + 4);
  bf16x8 v;
  v[0] = (bf16_t)a.x; v[1] = (bf16_t)a.y; v[2] = (bf16_t)a.z; v[3] = (bf16_t)a.w;
  v[4] = (bf16_t)b.x; v[5] = (bf16_t)b.y; v[6] = (bf16_t)b.z; v[7] = (bf16_t)b.w;
  *(bf16x8*)(dst + i) = v;
}

// final h: slot-1 values are epoch-1 encoded (sign-flipped) -> decode
__global__ void conv_dec_f32(const unsigned short* __restrict__ src,
                             float* __restrict__ dst, long n) {
  long i = (long)blockIdx.x * blockDim.x + threadIdx.x;
  if (i >= n) return;
  unsigned int u = ((unsigned int)(src[i] ^ 0x8000u)) << 16;
  dst[i] = __builtin_bit_cast(float, u);
}

__global__ void transpose_conv(const float* __restrict__ src,
                               bf16_t* __restrict__ dst, int Ksrc, int Nsrc) {
  __shared__ float tile[32][33];
  int n0 = blockIdx.x * 32, k0 = blockIdx.y * 32;
  int tx = threadIdx.x, ty = threadIdx.y;  // (32, 8)
#pragma unroll
  for (int i = 0; i < 32; i += 8)
    tile[ty + i][tx] = src[(long)(k0 + ty + i) * Nsrc + n0 + tx];
  __syncthreads();
#pragma unroll
  for (int i = 0; i < 32; i += 8)
    dst[(long)(n0 + ty + i) * Ksrc + k0 + tx] = (bf16_t)tile[tx][ty + i];
}

// ---------------------------------------------------------------------------
template <int STORE_MODE>
__global__ __launch_bounds__(256) void gemm_bt_128(
    const bf16_t* __restrict__ A, const bf16_t* __restrict__ Bt,
    const float* __restrict__ bias, void* __restrict__ Dout,
    int M, int N, int K) {
  __shared__ bf16_t As[128 * 32];
  __shared__ bf16_t Bs[128 * 32];
  const int tid = threadIdx.x;
  const int lane = tid & 63;
  const int w = tid >> 6;
  const int wr = w >> 1, wc = w & 1;
  const int m0 = blockIdx.y * 128, n0 = blockIdx.x * 128;

  f32x4 acc[4][4] = {};

  const int r0 = tid >> 2;
  const int kk = (tid & 3) * 8;
  const int fr = lane & 15;
  const int fk = (lane >> 4) * 8;

  for (int k0 = 0; k0 < K; k0 += 32) {
    load_lds16(A + (long)(m0 + r0) * K + k0 + kk, As + w * 512);
    load_lds16(A + (long)(m0 + 64 + r0) * K + k0 + kk, As + 2048 + w * 512);
    load_lds16(Bt + (long)(n0 + r0) * K + k0 + kk, Bs + w * 512);
    load_lds16(Bt + (long)(n0 + 64 + r0) * K + k0 + kk, Bs + 2048 + w * 512);
    asm volatile("s_waitcnt vmcnt(0)" ::: "memory");
    __syncthreads();

    bf16x8 af[4], bfx[4];
#pragma unroll
    for (int m = 0; m < 4; ++m)
      af[m] = *(const bf16x8*)&As[(wr * 64 + m * 16 + fr) * 32 + fk];
#pragma unroll
    for (int n = 0; n < 4; ++n)
      bfx[n] = *(const bf16x8*)&Bs[(wc * 64 + n * 16 + fr) * 32 + fk];
#pragma unroll
    for (int m = 0; m < 4; ++m)
#pragma unroll
      for (int n = 0; n < 4; ++n)
        acc[m][n] = __builtin_amdgcn_mfma_f32_16x16x32_bf16(af[m], bfx[n],
                                                            acc[m][n], 0, 0, 0);
    __syncthreads();
  }

  const int fq = lane >> 4;
#pragma unroll
  for (int m = 0; m < 4; ++m) {
#pragma unroll
    for (int n = 0; n < 4; ++n) {
      int col = n0 + wc * 64 + n * 16 + fr;
      float bv = bias[col];
#pragma unroll
      for (int r = 0; r < 4; ++r) {
        int row = m0 + wr * 64 + m * 16 + fq * 4 + r;
        float v = acc[m][n][r] + bv;
        if (STORE_MODE == 0)
          ((float*)Dout)[(long)row * N + col] = v;
        else
          ((bf16_t*)Dout)[(long)row * N + col] = (bf16_t)v;
      }
    }
  }
}

// ---------------------------------------------------------------------------
__device__ __forceinline__ void half_bar(unsigned int* c, unsigned int target,
                                         int lane) {
  if (lane == 0)
    __hip_atomic_fetch_add(c, 1u, __ATOMIC_RELEASE,
                           __HIP_MEMORY_SCOPE_WORKGROUP);
  unsigned int v;
  do {
    v = __hip_atomic_load(c, __ATOMIC_ACQUIRE, __HIP_MEMORY_SCOPE_WORKGROUP);
    if (v >= target) break;
    __builtin_amdgcn_s_sleep(1);
  } while (true);
}

// A-frag blob: 16x dwordx4 sc0 sc1 + vmcnt(0)
#define ABLOB(P)                                                              \
  asm volatile(                                                               \
      "global_load_dwordx4 %0, %16, off sc0 sc1\n\t"                          \
      "global_load_dwordx4 %1, %16, off offset:64 sc0 sc1\n\t"                \
      "global_load_dwordx4 %2, %16, off offset:128 sc0 sc1\n\t"               \
      "global_load_dwordx4 %3, %16, off offset:192 sc0 sc1\n\t"               \
      "global_load_dwordx4 %4, %16, off offset:256 sc0 sc1\n\t"               \
      "global_load_dwordx4 %5, %16, off offset:320 sc0 sc1\n\t"               \
      "global_load_dwordx4 %6, %16, off offset:384 sc0 sc1\n\t"               \
      "global_load_dwordx4 %7, %16, off offset:448 sc0 sc1\n\t"               \
      "global_load_dwordx4 %8, %16, off offset:512 sc0 sc1\n\t"               \
      "global_load_dwordx4 %9, %16, off offset:576 sc0 sc1\n\t"               \
      "global_load_dwordx4 %10, %16, off offset:640 sc0 sc1\n\t"              \
      "global_load_dwordx4 %11, %16, off offset:704 sc0 sc1\n\t"              \
      "global_load_dwordx4 %12, %16, off offset:768 sc0 sc1\n\t"              \
      "global_load_dwordx4 %13, %16, off offset:832 sc0 sc1\n\t"              \
      "global_load_dwordx4 %14, %16, off offset:896 sc0 sc1\n\t"              \
      "global_load_dwordx4 %15, %16, off offset:960 sc0 sc1\n\t"              \
      "s_waitcnt vmcnt(0)"                                                    \
      : "=&v"(a0), "=&v"(a1), "=&v"(a2), "=&v"(a3), "=&v"(a4), "=&v"(a5),     \
        "=&v"(a6), "=&v"(a7), "=&v"(a8), "=&v"(a9), "=&v"(a10), "=&v"(a11),   \
        "=&v"(a12), "=&v"(a13), "=&v"(a14), "=&v"(a15)                        \
      : "v"(P)                                                                \
      : "memory")

// ---------------------------------------------------------------------------
// Persistent recurrence v17 = v16 with the s_sleep(const) fix.
// DATA-AS-FLAG sign-epoch sync: h >= 0 (ReLU) -> sign bit 0.  h stored in a
// 2-slot rotating buffer (slot t&1), XOR 0x80008000 when epoch=(t>>1)&1 is 1.
// Consumer polls ITS OWN A-frag loads (sc0sc1): ready iff every dword's sign
// bits match the expected epoch.  Slots memset 0xAA every launch.
// Removes from critical path: producer drain, flag store, flag hop,
// post-detect A-load.  WAR: poll backpressure (writer at t+2 implies
// producers consumed h_t).  Q-fusion/rotating epilogues: v14-identical.
// ---------------------------------------------------------------------------
__global__ __launch_bounds__(512, 1) void rnn_persistent17(
    const bf16_t* __restrict__ h0,
    const bf16_t* __restrict__ Zbuf,  // (T,B,H) bf16, read-only (Z = xW+bh)
    bf16_t* __restrict__ Hslots,      // 2 x (B,H) bf16, sign-epoch encoded
    const bf16_t* __restrict__ WhhT,  // (2048 cols, 2048 K) bf16
    const bf16_t* __restrict__ WhqT,  // (1024 qcols, 2048 K) bf16
    const float* __restrict__ bq,     // (1024,)
    float* __restrict__ out) {        // (T*B, 1024) fp32
  __shared__ bf16_t Wlds[65536];          // 128 KB
  __shared__ float sred[2][4][16 * 36];   // 18.4 KB
  __shared__ bf16_t qred[2][4][16 * 20];  // 5 KB
  __shared__ unsigned int barc[2];
  __shared__ unsigned int sfree[2];
  __shared__ unsigned int qbc[2];
  __shared__ unsigned int qfree[2];

  const int tid = threadIdx.x, lane = tid & 63, w = tid >> 6;
  const int h = w >> 2;               // half 0/1
  const int lw = w & 3;               // wave within half
  const int gid = blockIdx.x;
  const int p = (gid >> 1) & 3;
  const int n0idx = ((gid & 1) << 5) | (gid >> 3);  // 0..63
  const int chain = p + h * 4;        // row group 0..7
  const int m0 = chain * 16, n0 = n0idx * 32;
  const int H = 2048;
  const long BH = 128L * 2048;        // one (B,H) slab
  const int kb = lw * 512;            // wave K-slab
  const int fr = lane & 15, fg = lane >> 4;
  const int w64 = lw * 64;
  const int qcol0 = n0idx * 16;

  // ---- stage W_hh cols [n0, n0+32) into LDS (once) ----
  {
    const int scol = tid >> 4;
    const int sk16 = tid & 15;
    const bf16_t* gsrc = WhhT + (long)(n0 + scol) * H + sk16 * 8;
#pragma unroll 4
    for (int j = 0; j < 16; ++j) {
      bf16x8 v = *(const bf16x8*)(gsrc + j * 128);
      int k8 = sk16 + j * 16;
      *(bf16x8*)&Wlds[(k8 * 32 + scol) * 8] = v;
    }
  }
  if (tid < 2) { barc[tid] = 0; sfree[tid] = 0; qbc[tid] = 0; qfree[tid] = 0; }

  // ---- W_hq slice pinned: 16 named bf16x8 (64 VGPR) ----
  const bf16_t* Wq = WhqT + (long)(qcol0 + fr) * H + kb + fg * 8;
#define LOADPIN(dst, off)                                                     \
  bf16x8 dst = *(const bf16x8*)(Wq + (off));                                  \
  {                                                                           \
    f32x4 t_ = __builtin_bit_cast(f32x4, dst);                                \
    asm volatile("" : "+v"(t_));                                              \
    dst = __builtin_bit_cast(bf16x8, t_);                                     \
  }
  LOADPIN(q0, 0)    LOADPIN(q1, 32)   LOADPIN(q2, 64)   LOADPIN(q3, 96)
  LOADPIN(q4, 128)  LOADPIN(q5, 160)  LOADPIN(q6, 192)  LOADPIN(q7, 224)
  LOADPIN(q8, 256)  LOADPIN(q9, 288)  LOADPIN(q10, 320) LOADPIN(q11, 352)
  LOADPIN(q12, 384) LOADPIN(q13, 416) LOADPIN(q14, 448) LOADPIN(q15, 480)
#undef LOADPIN
  __syncthreads();

  if (h == 1) __builtin_amdgcn_s_sleep(64);

  // h-epilogue ownership: lane e -> row e>>2, cols (e&3)*8..+8
  const int zrowW = lane >> 2, zcolW = (lane & 3) * 8;
  const int sidx = zrowW * 36 + zcolW;
  const long zoffW = (long)(m0 + zrowW) * H + n0 + zcolW;

  // q-epilogue ownership
  const int qrow = lane >> 2, qc4 = (lane & 3) * 4;
  const f32x4 bqv = *(const f32x4*)(bq + qcol0 + qc4);

  unsigned int* bc = &barc[h];
  unsigned int* sf = &sfree[h];
  unsigned int* qc = &qbc[h];
  unsigned int* qf = &qfree[h];

  const long aoff = (long)(m0 + fr) * H + kb + fg * 8;

  for (int t = 0; t < 256; ++t) {
    const bf16_t* z = Zbuf + (long)t * BH;
    const int ew = t & 3;          // h-epilogue wave
    const int ew2 = (t + 2) & 3;   // q-epilogue wave

    // ---- Z prefetch (epilogue wave only; read-only data, plain cached) ----
    f32x4 zvr = {};
    if (lw == ew) zvr = *(const f32x4*)(z + zoffW);

    // ---- A-frags with DATA-POLL (sign-epoch) ----
    f32x4 a0, a1, a2, a3, a4, a5, a6, a7, a8, a9, a10, a11, a12, a13, a14, a15;
    if (t == 0) {
      const bf16_t* Ab = h0 + aoff;
      ABLOB(Ab);
      __builtin_amdgcn_sched_barrier(0);
    } else {
      const bf16_t* Ab = Hslots + ((long)((t - 1) & 1)) * BH + aoff;
      const unsigned int expect =
          (((t - 1) >> 1) & 1) ? 0x80008000u : 0u;
      for (;;) {
        ABLOB(Ab);
        __builtin_amdgcn_sched_barrier(0);
        bool rdy;
        if (expect) {
          u32x4 m = __builtin_bit_cast(u32x4, a0);
          m &= __builtin_bit_cast(u32x4, a1);  m &= __builtin_bit_cast(u32x4, a2);
          m &= __builtin_bit_cast(u32x4, a3);  m &= __builtin_bit_cast(u32x4, a4);
          m &= __builtin_bit_cast(u32x4, a5);  m &= __builtin_bit_cast(u32x4, a6);
          m &= __builtin_bit_cast(u32x4, a7);  m &= __builtin_bit_cast(u32x4, a8);
          m &= __builtin_bit_cast(u32x4, a9);  m &= __builtin_bit_cast(u32x4, a10);
          m &= __builtin_bit_cast(u32x4, a11); m &= __builtin_bit_cast(u32x4, a12);
          m &= __builtin_bit_cast(u32x4, a13); m &= __builtin_bit_cast(u32x4, a14);
          m &= __builtin_bit_cast(u32x4, a15);
          unsigned int c = m[0] & m[1] & m[2] & m[3];
          rdy = ((~c) & 0x80008000u) == 0u;
        } else {
          u32x4 m = __builtin_bit_cast(u32x4, a0);
          m |= __builtin_bit_cast(u32x4, a1);  m |= __builtin_bit_cast(u32x4, a2);
          m |= __builtin_bit_cast(u32x4, a3);  m |= __builtin_bit_cast(u32x4, a4);
          m |= __builtin_bit_cast(u32x4, a5);  m |= __builtin_bit_cast(u32x4, a6);
          m |= __builtin_bit_cast(u32x4, a7);  m |= __builtin_bit_cast(u32x4, a8);
          m |= __builtin_bit_cast(u32x4, a9);  m |= __builtin_bit_cast(u32x4, a10);
          m |= __builtin_bit_cast(u32x4, a11); m |= __builtin_bit_cast(u32x4, a12);
          m |= __builtin_bit_cast(u32x4, a13); m |= __builtin_bit_cast(u32x4, a14);
          m |= __builtin_bit_cast(u32x4, a15);
          unsigned int c = m[0] | m[1] | m[2] | m[3];
          rdy = (c & 0x80008000u) == 0u;
        }
        if (__all(rdy)) break;
        __builtin_amdgcn_s_sleep(2);
      }
      if (expect) {  // decode: flip signs back
        const u32x4 msk = {0x80008000u, 0x80008000u, 0x80008000u, 0x80008000u};
#define DEC(A) A = __builtin_bit_cast(f32x4, __builtin_bit_cast(u32x4, A) ^ msk);
        DEC(a0) DEC(a1) DEC(a2) DEC(a3) DEC(a4) DEC(a5) DEC(a6) DEC(a7)
        DEC(a8) DEC(a9) DEC(a10) DEC(a11) DEC(a12) DEC(a13) DEC(a14) DEC(a15)
#undef DEC
      }
    }

    // ---- h-MFMAs (data already resident) ----
    f32x4 acc0 = {}, acc1 = {};
#define STEPX(ks, A)                                                          \
  {                                                                           \
    bf16x8 w0 = *(const bf16x8*)&Wlds[((w64 + (ks) * 4 + fg) * 32 + fr) * 8]; \
    bf16x8 w1 =                                                               \
        *(const bf16x8*)&Wlds[((w64 + (ks) * 4 + fg) * 32 + 16 + fr) * 8];    \
    bf16x8 av = __builtin_bit_cast(bf16x8, A);                                \
    acc0 = __builtin_amdgcn_mfma_f32_16x16x32_bf16(av, w0, acc0, 0, 0, 0);    \
    acc1 = __builtin_amdgcn_mfma_f32_16x16x32_bf16(av, w1, acc1, 0, 0, 0);    \
  }
    STEPX(0, a0)   STEPX(1, a1)   STEPX(2, a2)   STEPX(3, a3)
    STEPX(4, a4)   STEPX(5, a5)   STEPX(6, a6)   STEPX(7, a7)
    STEPX(8, a8)   STEPX(9, a9)   STEPX(10, a10) STEPX(11, a11)
    STEPX(12, a12) STEPX(13, a13) STEPX(14, a14) STEPX(15, a15)
#undef STEPX

    // ---- WAR guard: h-epilogue of step t-1 must have consumed sred ----
    if (t > 0) {
      while (__hip_atomic_load(sf, __ATOMIC_ACQUIRE,
                               __HIP_MEMORY_SCOPE_WORKGROUP) <
             (unsigned int)t)
        __builtin_amdgcn_s_sleep(1);
    }

    // ---- write h partials (padded stride 36) ----
#pragma unroll
    for (int rr = 0; rr < 4; ++rr) {
      sred[h][lw][(fg * 4 + rr) * 36 + fr] = acc0[rr];
      sred[h][lw][(fg * 4 + rr) * 36 + 16 + fr] = acc1[rr];
    }
    half_bar(bc, (unsigned int)(t + 1) * 4, lane);

    // ---- rotating-wave h-epilogue: reduce + Z + relu + encoded store ----
    if (lw == ew) {
      f32x4 slo = *(const f32x4*)&sred[h][0][sidx];
      f32x4 shi = *(const f32x4*)&sred[h][0][sidx + 4];
#pragma unroll
      for (int ww = 1; ww < 4; ++ww) {
        slo = slo + *(const f32x4*)&sred[h][ww][sidx];
        shi = shi + *(const f32x4*)&sred[h][ww][sidx + 4];
      }
      bf16x8 zv = __builtin_bit_cast(bf16x8, zvr);
      bf16x8 o;
#pragma unroll
      for (int c = 0; c < 4; ++c) {
        float v0 = slo[c] + (float)zv[c];
        float v1 = shi[c] + (float)zv[c + 4];
        o[c] = (bf16_t)(v0 > 0.f ? v0 : 0.f);
        o[c + 4] = (bf16_t)(v1 > 0.f ? v1 : 0.f);
      }
      u32x4 ov = __builtin_bit_cast(u32x4, o);
      if ((t >> 1) & 1) {
        const u32x4 msk = {0x80008000u, 0x80008000u, 0x80008000u, 0x80008000u};
        ov ^= msk;
      }
      bf16_t* hp = Hslots + ((long)(t & 1)) * BH + zoffW;
      {
        f32x4 of = __builtin_bit_cast(f32x4, ov);
        asm volatile("global_store_dwordx4 %0, %1, off sc0 sc1" ::"v"(hp),
                     "v"(of)
                     : "memory");
      }
      // NO drain, NO flag -- the data IS the flag.
      if (lane == 0)
        __hip_atomic_store(sf, (unsigned int)(t + 1), __ATOMIC_RELEASE,
                           __HIP_MEMORY_SCOPE_WORKGROUP);
    }

    // ======== FUSED Q-PROJECTION: out_{t-1} = h_{t-1} @ W_hq + b_q ========
    if (t > 0) {
      f32x4 qacc = {};
#define QSTEP(A, QW)                                                          \
  qacc = __builtin_amdgcn_mfma_f32_16x16x32_bf16(                             \
      __builtin_bit_cast(bf16x8, A), QW, qacc, 0, 0, 0);
      QSTEP(a0, q0)   QSTEP(a1, q1)   QSTEP(a2, q2)   QSTEP(a3, q3)
      QSTEP(a4, q4)   QSTEP(a5, q5)   QSTEP(a6, q6)   QSTEP(a7, q7)
      QSTEP(a8, q8)   QSTEP(a9, q9)   QSTEP(a10, q10) QSTEP(a11, q11)
      QSTEP(a12, q12) QSTEP(a13, q13) QSTEP(a14, q14) QSTEP(a15, q15)
#undef QSTEP
      while (__hip_atomic_load(qf, __ATOMIC_ACQUIRE,
                               __HIP_MEMORY_SCOPE_WORKGROUP) <
             (unsigned int)(t - 1))
        __builtin_amdgcn_s_sleep(1);
#pragma unroll
      for (int rr = 0; rr < 4; ++rr)
        qred[h][lw][(fg * 4 + rr) * 20 + fr] = (bf16_t)qacc[rr];
      half_bar(qc, (unsigned int)t * 4, lane);

      if (lw == ew2) {
        f32x4 s = bqv;
#pragma unroll
        for (int ww = 0; ww < 4; ++ww)
#pragma unroll
          for (int j = 0; j < 4; ++j)
            s[j] += (float)qred[h][ww][qrow * 20 + qc4 + j];
        float* op = out + ((long)(t - 1) * 128 + m0 + qrow) * 1024 + qcol0 + qc4;
        *(f32x4*)op = s;
        if (lane == 0)
          __hip_atomic_store(qf, (unsigned int)t, __ATOMIC_RELEASE,
                             __HIP_MEMORY_SCOPE_WORKGROUP);
      }
    }
  }

  // ======== post-loop: out_255 from h_255 (slot 1, epoch 1) ========
  {
    const bf16_t* Ab = Hslots + BH + aoff;
    f32x4 a0, a1, a2, a3, a4, a5, a6, a7, a8, a9, a10, a11, a12, a13, a14, a15;
    for (;;) {
      ABLOB(Ab);
      __builtin_amdgcn_sched_barrier(0);
      u32x4 m = __builtin_bit_cast(u32x4, a0);
      m &= __builtin_bit_cast(u32x4, a1);  m &= __builtin_bit_cast(u32x4, a2);
      m &= __builtin_bit_cast(u32x4, a3);  m &= __builtin_bit_cast(u32x4, a4);
      m &= __builtin_bit_cast(u32x4, a5);  m &= __builtin_bit_cast(u32x4, a6);
      m &= __builtin_bit_cast(u32x4, a7);  m &= __builtin_bit_cast(u32x4, a8);
      m &= __builtin_bit_cast(u32x4, a9);  m &= __builtin_bit_cast(u32x4, a10);
      m &= __builtin_bit_cast(u32x4, a11); m &= __builtin_bit_cast(u32x4, a12);
      m &= __builtin_bit_cast(u32x4, a13); m &= __builtin_bit_cast(u32x4, a14);
      m &= __builtin_bit_cast(u32x4, a15);
      unsigned int c = m[0] & m[1] & m[2] & m[3];
      if (__all(((~c) & 0x80008000u) == 0u)) break;
      __builtin_amdgcn_s_sleep(2);
    }
    {
      const u32x4 msk = {0x80008000u, 0x80008000u, 0x80008000u, 0x80008000u};
#define DEC(A) A = __builtin_bit_cast(f32x4, __builtin_bit_cast(u32x4, A) ^ msk);
      DEC(a0) DEC(a1) DEC(a2) DEC(a3) DEC(a4) DEC(a5) DEC(a6) DEC(a7)
      DEC(a8) DEC(a9) DEC(a10) DEC(a11) DEC(a12) DEC(a13) DEC(a14) DEC(a15)
#undef DEC
    }

    f32x4 qacc = {};
#define QSTEP(A, QW)                                                          \
  qacc = __builtin_amdgcn_mfma_f32_16x16x32_bf16(                             \
      __builtin_bit_cast(bf16x8, A), QW, qacc, 0, 0, 0);
    QSTEP(a0, q0)   QSTEP(a1, q1)   QSTEP(a2, q2)   QSTEP(a3, q3)
    QSTEP(a4, q4)   QSTEP(a5, q5)   QSTEP(a6, q6)   QSTEP(a7, q7)
    QSTEP(a8, q8)   QSTEP(a9, q9)   QSTEP(a10, q10) QSTEP(a11, q11)
    QSTEP(a12, q12) QSTEP(a13, q13) QSTEP(a14, q14) QSTEP(a15, q15)
#undef QSTEP
    while (__hip_atomic_load(qf, __ATOMIC_ACQUIRE,
                             __HIP_MEMORY_SCOPE_WORKGROUP) < 255u)
      __builtin_amdgcn_s_sleep(1);
#pragma unroll
    for (int rr = 0; rr < 4; ++rr)
      qred[h][lw][(fg * 4 + rr) * 20 + fr] = (bf16_t)qacc[rr];
    half_bar(qc, 256u * 4, lane);

    if (lw == ((256 + 2) & 3)) {
      f32x4 s = bqv;
#pragma unroll
      for (int ww = 0; ww < 4; ++ww)
#pragma unroll
        for (int j = 0; j < 4; ++j)
          s[j] += (float)qred[h][ww][qrow * 20 + qc4 + j];
      float* op = out + (255L * 128 + m0 + qrow) * 1024 + qcol0 + qc4;
      *(f32x4*)op = s;
    }
  }
}
#undef ABLOB

// ---------------------------------------------------------------------------
extern "C" void kernel_launch(void* const* d_in, const int* in_sizes, int n_in,
                              void* d_out, int out_size, void* d_ws,
                              size_t ws_size, hipStream_t stream) {
  const float* x   = (const float*)d_in[0];  // (T,B,D)
  const float* h0  = (const float*)d_in[1];  // (B,H)
  const float* Wxh = (const float*)d_in[2];  // (D,H)
  const float* Whh = (const float*)d_in[3];  // (H,H)
  const float* bh  = (const float*)d_in[4];  // (H,)
  const float* Whq = (const float*)d_in[5];  // (H,Q)
  const float* bq  = (const float*)d_in[6];  // (Q,)
  float* out = (float*)d_out;

  const int T = 256, B = 128, D = 1024, H = 2048, Q = 1024;
  const long MB = (long)T * B;  // 32768

  char* ws = (char*)d_ws;
  bf16_t* Hslots = (bf16_t*)ws;  ws += 2L * B * H * 2;       // 1 MiB (2 slots)
  bf16_t* x_bf = (bf16_t*)ws;  ws += MB * D * 2;             // 64 MiB
  bf16_t* Zbuf = (bf16_t*)ws;  ws += MB * H * 2;             // 128 MiB
  bf16_t* h0bf = (bf16_t*)ws;  ws += (long)B * H * 2;
  bf16_t* WxhT = (bf16_t*)ws;  ws += (long)H * D * 2;
  bf16_t* WhhT = (bf16_t*)ws;  ws += (long)H * H * 2;
  bf16_t* WhqT = (bf16_t*)ws;  ws += (long)Q * H * 2;

  // sentinel-init h slots EVERY launch (0xAA: sign bits 1 -> blocks epoch-0;
  // also makes replays identical to first run)
  hipMemsetAsync(Hslots, 0xAA, 2L * B * H * 2, stream);

  // --- convert inputs to bf16 (weights transposed to N x K) ---
  conv_f32_bf16<<<(int)(MB * D / 8 / 256), 256, 0, stream>>>(x, x_bf, MB * D);
  conv_f32_bf16<<<(int)((long)B * H / 8 / 256), 256, 0, stream>>>(h0, h0bf,
                                                                  (long)B * H);
  transpose_conv<<<dim3(H / 32, D / 32), dim3(32, 8), 0, stream>>>(Wxh, WxhT, D, H);
  transpose_conv<<<dim3(H / 32, H / 32), dim3(32, 8), 0, stream>>>(Whh, WhhT, H, H);
  transpose_conv<<<dim3(Q / 32, H / 32), dim3(32, 8), 0, stream>>>(Whq, WhqT, H, Q);

  // --- Z = x @ W_xh + b_h  (all timesteps), bf16 into Zbuf ---
  gemm_bt_128<1><<<dim3(H / 128, MB / 128), 256, 0, stream>>>(
      x_bf, WxhT, bh, Zbuf, (int)MB, H, D);

  // --- recurrence + fused Q-projection, data-as-flag sync ---
  rnn_persistent17<<<256, 512, 0, stream>>>(h0bf, Zbuf, Hslots, WhhT, WhqT,
                                            bq, out);

  // --- final h (fp32): slot 1 holds h_255 epoch-1 encoded -> decode ---
  conv_dec_f32<<<(int)((long)B * H / 256), 256, 0, stream>>>(
      (const unsigned short*)(Hslots + (long)B * H), out + MB * Q,
      (long)B * H);
}

// Round 20
// 1532.189 us; speedup vs baseline: 1.2353x; 1.2353x over previous
//
#include <hip/hip_runtime.h>
#include <hip/hip_bf16.h>

typedef __bf16 bf16_t;
typedef bf16_t bf16x8 __attribute__((ext_vector_type(8)));
typedef float f32x4 __attribute__((ext_vector_type(4)));

// ---------------------------------------------------------------------------
__device__ __forceinline__ void load_lds16(const bf16_t* g, bf16_t* l) {
  __builtin_amdgcn_global_load_lds(
      (const __attribute__((address_space(1))) unsigned int*)g,
      (__attribute__((address_space(3))) unsigned int*)l,
      16, 0, 0);
}

// ---------------------------------------------------------------------------
__global__ void conv_f32_bf16(const float* __restrict__ src,
                              bf16_t* __restrict__ dst, long n) {
  long i = ((long)blockIdx.x * blockDim.x + threadIdx.x) * 8;
  if (i + 7 >= n) return;
  float4 a = *(const float4*)(src + i);
  float4 b = *(const float4*)(src + i + 4);
  bf16x8 v;
  v[0] = (bf16_t)a.x; v[1] = (bf16_t)a.y; v[2] = (bf16_t)a.z; v[3] = (bf16_t)a.w;
  v[4] = (bf16_t)b.x; v[5] = (bf16_t)b.y; v[6] = (bf16_t)b.z; v[7] = (bf16_t)b.w;
  *(bf16x8*)(dst + i) = v;
}

__global__ void transpose_conv(const float* __restrict__ src,
                               bf16_t* __restrict__ dst, int Ksrc, int Nsrc) {
  __shared__ float tile[32][33];
  int n0 = blockIdx.x * 32, k0 = blockIdx.y * 32;
  int tx = threadIdx.x, ty = threadIdx.y;  // (32, 8)
#pragma unroll
  for (int i = 0; i < 32; i += 8)
    tile[ty + i][tx] = src[(long)(k0 + ty + i) * Nsrc + n0 + tx];
  __syncthreads();
#pragma unroll
  for (int i = 0; i < 32; i += 8)
    dst[(long)(n0 + ty + i) * Ksrc + k0 + tx] = (bf16_t)tile[tx][ty + i];
}

// ---------------------------------------------------------------------------
template <int STORE_MODE>
__global__ __launch_bounds__(256) void gemm_bt_128(
    const bf16_t* __restrict__ A, const bf16_t* __restrict__ Bt,
    const float* __restrict__ bias, void* __restrict__ Dout,
    int M, int N, int K) {
  __shared__ bf16_t As[128 * 32];
  __shared__ bf16_t Bs[128 * 32];
  const int tid = threadIdx.x;
  const int lane = tid & 63;
  const int w = tid >> 6;
  const int wr = w >> 1, wc = w & 1;
  const int m0 = blockIdx.y * 128, n0 = blockIdx.x * 128;

  f32x4 acc[4][4] = {};

  const int r0 = tid >> 2;
  const int kk = (tid & 3) * 8;
  const int fr = lane & 15;
  const int fk = (lane >> 4) * 8;

  for (int k0 = 0; k0 < K; k0 += 32) {
    load_lds16(A + (long)(m0 + r0) * K + k0 + kk, As + w * 512);
    load_lds16(A + (long)(m0 + 64 + r0) * K + k0 + kk, As + 2048 + w * 512);
    load_lds16(Bt + (long)(n0 + r0) * K + k0 + kk, Bs + w * 512);
    load_lds16(Bt + (long)(n0 + 64 + r0) * K + k0 + kk, Bs + 2048 + w * 512);
    asm volatile("s_waitcnt vmcnt(0)" ::: "memory");
    __syncthreads();

    bf16x8 af[4], bfx[4];
#pragma unroll
    for (int m = 0; m < 4; ++m)
      af[m] = *(const bf16x8*)&As[(wr * 64 + m * 16 + fr) * 32 + fk];
#pragma unroll
    for (int n = 0; n < 4; ++n)
      bfx[n] = *(const bf16x8*)&Bs[(wc * 64 + n * 16 + fr) * 32 + fk];
#pragma unroll
    for (int m = 0; m < 4; ++m)
#pragma unroll
      for (int n = 0; n < 4; ++n)
        acc[m][n] = __builtin_amdgcn_mfma_f32_16x16x32_bf16(af[m], bfx[n],
                                                            acc[m][n], 0, 0, 0);
    __syncthreads();
  }

  const int fq = lane >> 4;
#pragma unroll
  for (int m = 0; m < 4; ++m) {
#pragma unroll
    for (int n = 0; n < 4; ++n) {
      int col = n0 + wc * 64 + n * 16 + fr;
      float bv = bias[col];
#pragma unroll
      for (int r = 0; r < 4; ++r) {
        int row = m0 + wr * 64 + m * 16 + fq * 4 + r;
        float v = acc[m][n][r] + bv;
        if (STORE_MODE == 0)
          ((float*)Dout)[(long)row * N + col] = v;
        else
          ((bf16_t*)Dout)[(long)row * N + col] = (bf16_t)v;
      }
    }
  }
}

// ---------------------------------------------------------------------------
// Split barrier: everyone arrives (release); only the consumer wave waits.
// WAR reuse of the LDS buffers is separately guarded by sf/qf epochs.
// ---------------------------------------------------------------------------
__device__ __forceinline__ void bar_arrive(unsigned int* c, int lane) {
  if (lane == 0)
    __hip_atomic_fetch_add(c, 1u, __ATOMIC_RELEASE,
                           __HIP_MEMORY_SCOPE_WORKGROUP);
}
__device__ __forceinline__ void bar_wait(unsigned int* c,
                                         unsigned int target) {
  unsigned int v;
  do {
    v = __hip_atomic_load(c, __ATOMIC_ACQUIRE, __HIP_MEMORY_SCOPE_WORKGROUP);
    if (v >= target) break;
    __builtin_amdgcn_s_sleep(1);
  } while (true);
}

// ---------------------------------------------------------------------------
// Persistent recurrence v18 = v14 (proven 1564us champion) + two changes:
//  1. SPLIT BARRIERS: bar_arrive for all waves; bar_wait only in the
//     epilogue-wave branch.  Non-epilogue waves flow sred->arrive->Q-phase->
//     qred->arrive->NEXT POLL, so the next step's flag detect + ~900cy A-fill
//     overlap the laggard wave's h-epilogue + Q-MFMAs (v14's q-half_bar had
//     serialized those into every wave's path).
//  2. post-loop writes fp32 final-h directly (n0idx==0 WGs, A-frags already
//     in registers) -> conv_bf16_f32 launch deleted.
// Protocol (padded flags, sc0sc1 h stores, sc0 A loads, no fences), Q-fusion,
// rotating epilogues, sf/qf epochs: v14-identical.
// ---------------------------------------------------------------------------
__global__ __launch_bounds__(512, 1) void rnn_persistent18(
    const bf16_t* __restrict__ h0,
    bf16_t* __restrict__ Hbuf,        // Z in, h out, (T,B,H) bf16
    const bf16_t* __restrict__ WhhT,  // (2048 cols, 2048 K) bf16
    const bf16_t* __restrict__ WhqT,  // (1024 qcols, 2048 K) bf16
    const float* __restrict__ bq,     // (1024,)
    float* __restrict__ out,          // (T*B, 1024) fp32 ++ (B,H) fp32
    unsigned int* __restrict__ flags) {  // 512 flags, 64B apart, pre-zeroed
  __shared__ bf16_t Wlds[65536];          // 128 KB
  __shared__ float sred[2][4][16 * 36];   // 18.4 KB
  __shared__ bf16_t qred[2][4][16 * 20];  // 5 KB
  __shared__ unsigned int barc[2];
  __shared__ unsigned int sfree[2];
  __shared__ unsigned int qbc[2];
  __shared__ unsigned int qfree[2];

  const int tid = threadIdx.x, lane = tid & 63, w = tid >> 6;
  const int h = w >> 2;               // half 0/1
  const int lw = w & 3;               // wave within half
  const int gid = blockIdx.x;
  const int p = (gid >> 1) & 3;
  const int n0idx = ((gid & 1) << 5) | (gid >> 3);  // 0..63
  const int chain = p + h * 4;        // row group 0..7
  const int m0 = chain * 16, n0 = n0idx * 32;
  const int H = 2048;
  const long BH = 128L * 2048;
  const int kb = lw * 512;            // wave K-slab
  const int fr = lane & 15, fg = lane >> 4;
  const int w64 = lw * 64;            // k8 base of slab
  const int qcol0 = n0idx * 16;       // this half-WG's 16 Q-cols

  // ---- stage W_hh cols [n0, n0+32) into LDS (once, all 512 threads) ----
  {
    const int scol = tid >> 4;          // 0..31
    const int sk16 = tid & 15;
    const bf16_t* gsrc = WhhT + (long)(n0 + scol) * H + sk16 * 8;
#pragma unroll 4
    for (int j = 0; j < 16; ++j) {
      bf16x8 v = *(const bf16x8*)(gsrc + j * 128);
      int k8 = sk16 + j * 16;
      *(bf16x8*)&Wlds[(k8 * 32 + scol) * 8] = v;
    }
  }
  if (tid < 2) { barc[tid] = 0; sfree[tid] = 0; qbc[tid] = 0; qfree[tid] = 0; }

  // ---- W_hq slice pinned in VGPRs: 16 named bf16x8 (64 VGPR/lane) ----
  const bf16_t* Wq = WhqT + (long)(qcol0 + fr) * H + kb + fg * 8;
#define LOADPIN(dst, off)                                                     \
  bf16x8 dst = *(const bf16x8*)(Wq + (off));                                  \
  {                                                                           \
    f32x4 t_ = __builtin_bit_cast(f32x4, dst);                                \
    asm volatile("" : "+v"(t_));                                              \
    dst = __builtin_bit_cast(bf16x8, t_);                                     \
  }
  LOADPIN(q0, 0)    LOADPIN(q1, 32)   LOADPIN(q2, 64)   LOADPIN(q3, 96)
  LOADPIN(q4, 128)  LOADPIN(q5, 160)  LOADPIN(q6, 192)  LOADPIN(q7, 224)
  LOADPIN(q8, 256)  LOADPIN(q9, 288)  LOADPIN(q10, 320) LOADPIN(q11, 352)
  LOADPIN(q12, 384) LOADPIN(q13, 416) LOADPIN(q14, 448) LOADPIN(q15, 480)
#undef LOADPIN
  __syncthreads();  // ONLY whole-WG barrier; halves decoupled after this

  // anti-phase stagger: half 1 starts ~1.7us late (chains are independent)
  if (h == 1) __builtin_amdgcn_s_sleep(64);

  // h-epilogue ownership: lane e -> row e>>2, cols (e&3)*8..+8
  const int zrowW = lane >> 2, zcolW = (lane & 3) * 8;
  const int sidx = zrowW * 36 + zcolW;
  const long zoffW = (long)(m0 + zrowW) * H + n0 + zcolW;

  // q-epilogue ownership: lane -> row lane>>2, 4 cols (lane&3)*4
  const int qrow = lane >> 2, qc4 = (lane & 3) * 4;
  const f32x4 bqv = *(const f32x4*)(bq + qcol0 + qc4);

  unsigned int* myflag = flags + (((chain << 6) | n0idx) << 4);
  const unsigned int* pollflag =
      flags + (((chain << 6) | (lw * 16 + (lane & 15))) << 4);
  unsigned int* bc = &barc[h];
  unsigned int* sf = &sfree[h];
  unsigned int* qc = &qbc[h];
  unsigned int* qf = &qfree[h];

  for (int t = 0; t < 256; ++t) {
    const bf16_t* hp = (t == 0) ? h0 : Hbuf + (long)(t - 1) * BH;
    bf16_t* z = Hbuf + (long)t * BH;
    const int ew = t & 3;          // h-epilogue wave
    const int ew2 = (t + 2) & 3;   // q-epilogue wave (different)

    // ---- Z prefetch (h-epilogue wave only, 16B/lane, sc0sc1) ----
    f32x4 zvr;
    if (lw == ew) {
      const bf16_t* zp = z + zoffW;
      asm volatile("global_load_dwordx4 %0, %1, off sc0 sc1"
                   : "=v"(zvr)
                   : "v"(zp)
                   : "memory");
    }

    // ---- poll my K-slab's 16 producer flags, light backoff ----
    if (t > 0) {
      const unsigned int tt = (unsigned int)t;
      unsigned int v = __hip_atomic_load(pollflag, __ATOMIC_RELAXED,
                                         __HIP_MEMORY_SCOPE_AGENT);
      if (!__all(v >= tt)) {
        __builtin_amdgcn_s_sleep(1);
        v = __hip_atomic_load(pollflag, __ATOMIC_RELAXED,
                              __HIP_MEMORY_SCOPE_AGENT);
        if (!__all(v >= tt)) {
          __builtin_amdgcn_s_sleep(2);
          v = __hip_atomic_load(pollflag, __ATOMIC_RELAXED,
                                __HIP_MEMORY_SCOPE_AGENT);
          if (!__all(v >= tt)) {
            __builtin_amdgcn_s_sleep(4);
            v = __hip_atomic_load(pollflag, __ATOMIC_RELAXED,
                                  __HIP_MEMORY_SCOPE_AGENT);
            while (!__all(v >= tt)) {
              __builtin_amdgcn_s_sleep(8);
              v = __hip_atomic_load(pollflag, __ATOMIC_RELAXED,
                                    __HIP_MEMORY_SCOPE_AGENT);
            }
          }
        }
      }
    }

    // ---- A-frags: 16 rows (fr) x K-slab 512 of h_{t-1}, sc0 ----
    const bf16_t* Ab = hp + (long)(m0 + fr) * H + kb + fg * 8;
    f32x4 a0, a1, a2, a3, a4, a5, a6, a7, a8, a9, a10, a11, a12, a13, a14, a15;
    asm volatile(
        "global_load_dwordx4 %0, %16, off sc0\n\t"
        "global_load_dwordx4 %1, %16, off offset:64 sc0\n\t"
        "global_load_dwordx4 %2, %16, off offset:128 sc0\n\t"
        "global_load_dwordx4 %3, %16, off offset:192 sc0\n\t"
        "global_load_dwordx4 %4, %16, off offset:256 sc0\n\t"
        "global_load_dwordx4 %5, %16, off offset:320 sc0\n\t"
        "global_load_dwordx4 %6, %16, off offset:384 sc0\n\t"
        "global_load_dwordx4 %7, %16, off offset:448 sc0\n\t"
        "global_load_dwordx4 %8, %16, off offset:512 sc0\n\t"
        "global_load_dwordx4 %9, %16, off offset:576 sc0\n\t"
        "global_load_dwordx4 %10, %16, off offset:640 sc0\n\t"
        "global_load_dwordx4 %11, %16, off offset:704 sc0\n\t"
        "global_load_dwordx4 %12, %16, off offset:768 sc0\n\t"
        "global_load_dwordx4 %13, %16, off offset:832 sc0\n\t"
        "global_load_dwordx4 %14, %16, off offset:896 sc0\n\t"
        "global_load_dwordx4 %15, %16, off offset:960 sc0"
        : "=&v"(a0), "=&v"(a1), "=&v"(a2), "=&v"(a3), "=&v"(a4), "=&v"(a5),
          "=&v"(a6), "=&v"(a7), "=&v"(a8), "=&v"(a9), "=&v"(a10), "=&v"(a11),
          "=&v"(a12), "=&v"(a13), "=&v"(a14), "=&v"(a15)
        : "v"(Ab)
        : "memory");

    f32x4 acc0 = {}, acc1 = {};
#define STEPX(ks, A)                                                          \
  {                                                                           \
    bf16x8 w0 = *(const bf16x8*)&Wlds[((w64 + (ks) * 4 + fg) * 32 + fr) * 8]; \
    bf16x8 w1 =                                                               \
        *(const bf16x8*)&Wlds[((w64 + (ks) * 4 + fg) * 32 + 16 + fr) * 8];    \
    bf16x8 av = __builtin_bit_cast(bf16x8, A);                                \
    acc0 = __builtin_amdgcn_mfma_f32_16x16x32_bf16(av, w0, acc0, 0, 0, 0);    \
    acc1 = __builtin_amdgcn_mfma_f32_16x16x32_bf16(av, w1, acc1, 0, 0, 0);    \
  }
    // split wait: ew wave has Z(1)+A(16)=17 outstanding -> vmcnt(8) retires
    // Z + a0..a7; others have 16 -> retires a0..a7.
    asm volatile("s_waitcnt vmcnt(8)" ::: "memory");
    __builtin_amdgcn_sched_barrier(0);  // rule #18
    STEPX(0, a0)   STEPX(1, a1)   STEPX(2, a2)   STEPX(3, a3)
    STEPX(4, a4)   STEPX(5, a5)   STEPX(6, a6)   STEPX(7, a7)
    asm volatile("s_waitcnt vmcnt(0)" ::: "memory");
    __builtin_amdgcn_sched_barrier(0);
    STEPX(8, a8)   STEPX(9, a9)   STEPX(10, a10) STEPX(11, a11)
    STEPX(12, a12) STEPX(13, a13) STEPX(14, a14) STEPX(15, a15)
#undef STEPX

    // ---- WAR guard: h-epilogue of step t-1 must have consumed sred ----
    if (t > 0) {
      while (__hip_atomic_load(sf, __ATOMIC_ACQUIRE,
                               __HIP_MEMORY_SCOPE_WORKGROUP) <
             (unsigned int)t)
        __builtin_amdgcn_s_sleep(1);
    }

    // ---- write h partials (padded stride 36); arrive (no wait) ----
#pragma unroll
    for (int rr = 0; rr < 4; ++rr) {
      sred[h][lw][(fg * 4 + rr) * 36 + fr] = acc0[rr];
      sred[h][lw][(fg * 4 + rr) * 36 + 16 + fr] = acc1[rr];
    }
    bar_arrive(bc, lane);

    // ---- rotating-wave h-epilogue: waits alone, then reduce+store+flag ----
    if (lw == ew) {
      bar_wait(bc, (unsigned int)(t + 1) * 4);
      f32x4 slo = *(const f32x4*)&sred[h][0][sidx];
      f32x4 shi = *(const f32x4*)&sred[h][0][sidx + 4];
#pragma unroll
      for (int ww = 1; ww < 4; ++ww) {
        slo = slo + *(const f32x4*)&sred[h][ww][sidx];
        shi = shi + *(const f32x4*)&sred[h][ww][sidx + 4];
      }
      bf16x8 zv = __builtin_bit_cast(bf16x8, zvr);
      bf16x8 o;
#pragma unroll
      for (int c = 0; c < 4; ++c) {
        float v0 = slo[c] + (float)zv[c];
        float v1 = shi[c] + (float)zv[c + 4];
        o[c] = (bf16_t)(v0 > 0.f ? v0 : 0.f);
        o[c + 4] = (bf16_t)(v1 > 0.f ? v1 : 0.f);
      }
      const bf16_t* zp = z + zoffW;
      {
        f32x4 ov = __builtin_bit_cast(f32x4, o);
        asm volatile("global_store_dwordx4 %0, %1, off sc0 sc1" ::"v"(zp),
                     "v"(ov)
                     : "memory");
      }
      asm volatile("s_waitcnt vmcnt(0)" ::: "memory");  // tile visible in L3
      if (lane == 0) {
        __hip_atomic_store(myflag, (unsigned int)(t + 1), __ATOMIC_RELAXED,
                           __HIP_MEMORY_SCOPE_AGENT);
        __hip_atomic_store(sf, (unsigned int)(t + 1), __ATOMIC_RELEASE,
                           __HIP_MEMORY_SCOPE_WORKGROUP);
      }
    }

    // ======== FUSED Q-PROJECTION: out_{t-1} = h_{t-1} @ W_hq + b_q ========
    if (t > 0) {
      f32x4 qacc = {};
#define QSTEP(A, QW)                                                          \
  qacc = __builtin_amdgcn_mfma_f32_16x16x32_bf16(                             \
      __builtin_bit_cast(bf16x8, A), QW, qacc, 0, 0, 0);
      QSTEP(a0, q0)   QSTEP(a1, q1)   QSTEP(a2, q2)   QSTEP(a3, q3)
      QSTEP(a4, q4)   QSTEP(a5, q5)   QSTEP(a6, q6)   QSTEP(a7, q7)
      QSTEP(a8, q8)   QSTEP(a9, q9)   QSTEP(a10, q10) QSTEP(a11, q11)
      QSTEP(a12, q12) QSTEP(a13, q13) QSTEP(a14, q14) QSTEP(a15, q15)
#undef QSTEP
      // WAR: q-epilogue of previous generation must have consumed qred
      while (__hip_atomic_load(qf, __ATOMIC_ACQUIRE,
                               __HIP_MEMORY_SCOPE_WORKGROUP) <
             (unsigned int)(t - 1))
        __builtin_amdgcn_s_sleep(1);
#pragma unroll
      for (int rr = 0; rr < 4; ++rr)
        qred[h][lw][(fg * 4 + rr) * 20 + fr] = (bf16_t)qacc[rr];
      bar_arrive(qc, lane);

      if (lw == ew2) {
        bar_wait(qc, (unsigned int)t * 4);
        f32x4 s = bqv;
#pragma unroll
        for (int ww = 0; ww < 4; ++ww)
#pragma unroll
          for (int j = 0; j < 4; ++j)
            s[j] += (float)qred[h][ww][qrow * 20 + qc4 + j];
        float* op = out + ((long)(t - 1) * 128 + m0 + qrow) * 1024 + qcol0 + qc4;
        *(f32x4*)op = s;
        if (lane == 0)
          __hip_atomic_store(qf, (unsigned int)t, __ATOMIC_RELEASE,
                             __HIP_MEMORY_SCOPE_WORKGROUP);
      }
    }
  }

  // ======== post-loop: out_255 from h_255 + fp32 final-h ========
  {
    const unsigned int tt = 256u;
    unsigned int v;
    do {
      v = __hip_atomic_load(pollflag, __ATOMIC_RELAXED,
                            __HIP_MEMORY_SCOPE_AGENT);
      if (__all(v >= tt)) break;
      __builtin_amdgcn_s_sleep(2);
    } while (true);

    const bf16_t* hp = Hbuf + 255L * BH;
    const bf16_t* Ab = hp + (long)(m0 + fr) * H + kb + fg * 8;
    f32x4 a0, a1, a2, a3, a4, a5, a6, a7, a8, a9, a10, a11, a12, a13, a14, a15;
    asm volatile(
        "global_load_dwordx4 %0, %16, off sc0\n\t"
        "global_load_dwordx4 %1, %16, off offset:64 sc0\n\t"
        "global_load_dwordx4 %2, %16, off offset:128 sc0\n\t"
        "global_load_dwordx4 %3, %16, off offset:192 sc0\n\t"
        "global_load_dwordx4 %4, %16, off offset:256 sc0\n\t"
        "global_load_dwordx4 %5, %16, off offset:320 sc0\n\t"
        "global_load_dwordx4 %6, %16, off offset:384 sc0\n\t"
        "global_load_dwordx4 %7, %16, off offset:448 sc0\n\t"
        "global_load_dwordx4 %8, %16, off offset:512 sc0\n\t"
        "global_load_dwordx4 %9, %16, off offset:576 sc0\n\t"
        "global_load_dwordx4 %10, %16, off offset:640 sc0\n\t"
        "global_load_dwordx4 %11, %16, off offset:704 sc0\n\t"
        "global_load_dwordx4 %12, %16, off offset:768 sc0\n\t"
        "global_load_dwordx4 %13, %16, off offset:832 sc0\n\t"
        "global_load_dwordx4 %14, %16, off offset:896 sc0\n\t"
        "global_load_dwordx4 %15, %16, off offset:960 sc0\n\t"
        "s_waitcnt vmcnt(0)"
        : "=&v"(a0), "=&v"(a1), "=&v"(a2), "=&v"(a3), "=&v"(a4), "=&v"(a5),
          "=&v"(a6), "=&v"(a7), "=&v"(a8), "=&v"(a9), "=&v"(a10), "=&v"(a11),
          "=&v"(a12), "=&v"(a13), "=&v"(a14), "=&v"(a15)
        : "v"(Ab)
        : "memory");
    __builtin_amdgcn_sched_barrier(0);

    // fp32 final-h: 8 designated WGs (n0idx==0) cover all 128 rows x 2048 cols
    if (n0idx == 0) {
      float* hf = out + 32768L * 1024 + (long)(m0 + fr) * 2048 + kb + fg * 8;
#define HSTORE(ks, A)                                                         \
  {                                                                           \
    bf16x8 av = __builtin_bit_cast(bf16x8, A);                                \
    f32x4 lo, hi;                                                             \
    for (int j = 0; j < 4; ++j) {                                             \
      lo[j] = (float)av[j];                                                   \
      hi[j] = (float)av[j + 4];                                               \
    }                                                                         \
    *(f32x4*)(hf + (ks) * 32) = lo;                                           \
    *(f32x4*)(hf + (ks) * 32 + 4) = hi;                                       \
  }
      HSTORE(0, a0)   HSTORE(1, a1)   HSTORE(2, a2)   HSTORE(3, a3)
      HSTORE(4, a4)   HSTORE(5, a5)   HSTORE(6, a6)   HSTORE(7, a7)
      HSTORE(8, a8)   HSTORE(9, a9)   HSTORE(10, a10) HSTORE(11, a11)
      HSTORE(12, a12) HSTORE(13, a13) HSTORE(14, a14) HSTORE(15, a15)
#undef HSTORE
    }

    f32x4 qacc = {};
#define QSTEP(A, QW)                                                          \
  qacc = __builtin_amdgcn_mfma_f32_16x16x32_bf16(                             \
      __builtin_bit_cast(bf16x8, A), QW, qacc, 0, 0, 0);
    QSTEP(a0, q0)   QSTEP(a1, q1)   QSTEP(a2, q2)   QSTEP(a3, q3)
    QSTEP(a4, q4)   QSTEP(a5, q5)   QSTEP(a6, q6)   QSTEP(a7, q7)
    QSTEP(a8, q8)   QSTEP(a9, q9)   QSTEP(a10, q10) QSTEP(a11, q11)
    QSTEP(a12, q12) QSTEP(a13, q13) QSTEP(a14, q14) QSTEP(a15, q15)
#undef QSTEP
    while (__hip_atomic_load(qf, __ATOMIC_ACQUIRE,
                             __HIP_MEMORY_SCOPE_WORKGROUP) < 255u)
      __builtin_amdgcn_s_sleep(1);
#pragma unroll
    for (int rr = 0; rr < 4; ++rr)
      qred[h][lw][(fg * 4 + rr) * 20 + fr] = (bf16_t)qacc[rr];
    bar_arrive(qc, lane);

    if (lw == ((256 + 2) & 3)) {
      bar_wait(qc, 256u * 4);
      f32x4 s = bqv;
#pragma unroll
      for (int ww = 0; ww < 4; ++ww)
#pragma unroll
        for (int j = 0; j < 4; ++j)
          s[j] += (float)qred[h][ww][qrow * 20 + qc4 + j];
      float* op = out + (255L * 128 + m0 + qrow) * 1024 + qcol0 + qc4;
      *(f32x4*)op = s;
    }
  }
}

// ---------------------------------------------------------------------------
extern "C" void kernel_launch(void* const* d_in, const int* in_sizes, int n_in,
                              void* d_out, int out_size, void* d_ws,
                              size_t ws_size, hipStream_t stream) {
  const float* x   = (const float*)d_in[0];  // (T,B,D)
  const float* h0  = (const float*)d_in[1];  // (B,H)
  const float* Wxh = (const float*)d_in[2];  // (D,H)
  const float* Whh = (const float*)d_in[3];  // (H,H)
  const float* bh  = (const float*)d_in[4];  // (H,)
  const float* Whq = (const float*)d_in[5];  // (H,Q)
  const float* bq  = (const float*)d_in[6];  // (Q,)
  float* out = (float*)d_out;

  const int T = 256, B = 128, D = 1024, H = 2048, Q = 1024;
  const long MB = (long)T * B;  // 32768

  char* ws = (char*)d_ws;
  unsigned int* flags = (unsigned int*)ws;  ws += 512 * 64;  // padded flags
  bf16_t* x_bf = (bf16_t*)ws;  ws += MB * D * 2;             // 64 MiB
  bf16_t* Hbuf = (bf16_t*)ws;  ws += MB * H * 2;             // 128 MiB (Z->h)
  bf16_t* h0bf = (bf16_t*)ws;  ws += (long)B * H * 2;
  bf16_t* WxhT = (bf16_t*)ws;  ws += (long)H * D * 2;
  bf16_t* WhhT = (bf16_t*)ws;  ws += (long)H * H * 2;
  bf16_t* WhqT = (bf16_t*)ws;  ws += (long)Q * H * 2;

  hipMemsetAsync(flags, 0, 512 * 64, stream);

  // --- convert inputs to bf16 (weights transposed to N x K) ---
  conv_f32_bf16<<<(int)(MB * D / 8 / 256), 256, 0, stream>>>(x, x_bf, MB * D);
  conv_f32_bf16<<<(int)((long)B * H / 8 / 256), 256, 0, stream>>>(h0, h0bf,
                                                                  (long)B * H);
  transpose_conv<<<dim3(H / 32, D / 32), dim3(32, 8), 0, stream>>>(Wxh, WxhT, D, H);
  transpose_conv<<<dim3(H / 32, H / 32), dim3(32, 8), 0, stream>>>(Whh, WhhT, H, H);
  transpose_conv<<<dim3(Q / 32, H / 32), dim3(32, 8), 0, stream>>>(Whq, WhqT, H, Q);

  // --- Z = x @ W_xh + b_h  (all timesteps), bf16 into Hbuf ---
  gemm_bt_128<1><<<dim3(H / 128, MB / 128), 256, 0, stream>>>(
      x_bf, WxhT, bh, Hbuf, (int)MB, H, D);

  // --- recurrence + fused Q-projection + fp32 final-h, ONE kernel ---
  rnn_persistent18<<<256, 512, 0, stream>>>(h0bf, Hbuf, WhhT, WhqT, bq, out,
                                            flags);
}